// Round 5
// baseline (2947.207 us; speedup 1.0000x reference)
//
#include <hip/hip_runtime.h>

// GNN27: two-branch diffusion GCN (N=8192, F_IN=11, F1=16, F2=32) + multi-head
// tanh-attention pooling. All fp32. Memory-bound on the two 268MB adjacencies,
// each streamed twice -> 1.07GB unique traffic.
//
// R1: 256B-granular direct loads -> 680 GB/s. R2-R4: global_load_lds staging,
// any sync structure -> ~1 TB/s. Arithmetic: 7.3 GB/s/CU at ~400ns latency
// = ~3KB effective in flight vs 64KB nominal -> the global->LDS DMA path
// serializes requests (shallow FIFO). R5: stream A through REGISTERS with
// plain global_load_dwordx4 (the 6.3 TB/s m13 path), regs act as the second
// buffer, ds_write to a single per-wave LDS region for the kg/cg compute
// redistribution. Barrier-free; in-order vmcnt respected: P(t+1) issued
// BEFORE A(t+2) so the counted wait vmcnt(|A|) lands P without draining A.

constexpr int N = 8192;

// ---------------- kernel 1: P1 = x @ W1   ([N,11] @ [11,16]) ----------------
__global__ void k_dense_in(const float* __restrict__ x0, const float* __restrict__ x1,
                           const float* __restrict__ W0, const float* __restrict__ W1,
                           float* __restrict__ o0, float* __restrict__ o1) {
    const int branch = blockIdx.y;
    const float* __restrict__ x = branch ? x1 : x0;
    const float* __restrict__ W = branch ? W1 : W0;
    float* __restrict__ o = branch ? o1 : o0;
    __shared__ float sW[11 * 16];
    if (threadIdx.x < 176) sW[threadIdx.x] = W[threadIdx.x];
    __syncthreads();
    const int n = blockIdx.x * blockDim.x + threadIdx.x;  // grid.x*256 == N exactly
    float xr[11];
#pragma unroll
    for (int j = 0; j < 11; ++j) xr[j] = x[n * 11 + j];
    float acc[16];
#pragma unroll
    for (int f = 0; f < 16; ++f) acc[f] = 0.f;
#pragma unroll
    for (int j = 0; j < 11; ++j)
#pragma unroll
        for (int f = 0; f < 16; ++f) acc[f] += xr[j] * sW[j * 16 + f];
#pragma unroll
    for (int q = 0; q < 4; ++q) {
        float4 r = make_float4(acc[q * 4 + 0], acc[q * 4 + 1], acc[q * 4 + 2], acc[q * 4 + 3]);
        *reinterpret_cast<float4*>(&o[n * 16 + q * 4]) = r;
    }
}

// ---------------- kernel 3: P2 = H1 @ W2   ([N,16] @ [16,32]) ----------------
__global__ void k_dense_mid(const float* __restrict__ h0, const float* __restrict__ h1,
                            const float* __restrict__ W0, const float* __restrict__ W1,
                            float* __restrict__ o0, float* __restrict__ o1) {
    const int branch = blockIdx.y;
    const float* __restrict__ h = branch ? h1 : h0;
    const float* __restrict__ W = branch ? W1 : W0;
    float* __restrict__ o = branch ? o1 : o0;
    __shared__ float sW[16 * 32];
    for (int i = threadIdx.x; i < 512; i += blockDim.x) sW[i] = W[i];
    __syncthreads();
    const int n = blockIdx.x * blockDim.x + threadIdx.x;
    float hr[16];
#pragma unroll
    for (int q = 0; q < 4; ++q)
        *reinterpret_cast<float4*>(&hr[q * 4]) =
            *reinterpret_cast<const float4*>(&h[n * 16 + q * 4]);
    float acc[32];
#pragma unroll
    for (int f = 0; f < 32; ++f) acc[f] = 0.f;
#pragma unroll
    for (int j = 0; j < 16; ++j)
#pragma unroll
        for (int f = 0; f < 32; ++f) acc[f] += hr[j] * sW[j * 32 + f];
#pragma unroll
    for (int q = 0; q < 8; ++q) {
        float4 r = make_float4(acc[q * 4 + 0], acc[q * 4 + 1], acc[q * 4 + 2], acc[q * 4 + 3]);
        *reinterpret_cast<float4*>(&o[n * 32 + q * 4]) = r;
    }
}

// -------- kernels 2 & 4: H = relu(A @ P + b), reg-streamed A ---------------
// 4 independent waves/block (barrier-free). Wave owns R rows. Super-tile
// KT=512: A loaded as 2 consecutive dwordx4 per row per lane (2KB bursts) into
// regs; ds_write to per-wave LDS; compute reads LDS in kg/cg layout with P in
// regs. Pipeline per iter: compute(t) | vmcnt(0) -> ds_write A(t+1) ->
// issue P(t+1) -> issue A(t+2) -> vmcnt(2R) [P landed, A(t+2) flying].
template <int F, int R>
__global__ __launch_bounds__(256, 1) void k_spmm(
    const float* __restrict__ A0, const float* __restrict__ A1,
    const float* __restrict__ Pm0, const float* __restrict__ Pm1,
    const float* __restrict__ b0, const float* __restrict__ b1,
    float* __restrict__ o0, float* __restrict__ o1, int ostride) {
    constexpr int TN = F / 4;    // cols per thread: 4 (F=16) or 8 (F=32)
    constexpr int PJ = TN / 4;   // float4s of P per k: 1 or 2
    constexpr int KT = 512;      // super-tile
    constexpr int NT = N / KT;   // 16
    const int branch = blockIdx.y;
    const float* __restrict__ A = branch ? A1 : A0;
    const float* __restrict__ Pm = branch ? Pm1 : Pm0;
    const float* __restrict__ bias = branch ? b1 : b0;
    float* __restrict__ o = branch ? o1 : o0;

    __shared__ float lds[4 * R * KT];  // per-wave single buffer (regs = buf2)

    const int lane = threadIdx.x & 63;
    const int wave = threadIdx.x >> 6;
    const int kg = lane & 15;  // k-group
    const int cg = lane >> 4;  // col-group 0..3
    const int c0 = cg * TN;
    const int rowW = blockIdx.x * (4 * R) + wave * R;  // wave's first row
    const float* __restrict__ Abase = A + (size_t)rowW * N + lane * 4;
    float* __restrict__ wl = &lds[wave * R * KT];
    const int phase = (blockIdx.x * 4 + wave) & (NT - 1);  // K-rotation

    float4 a[R][2];
    float4 p[8][4][PJ];
    float acc[R][TN];
#pragma unroll
    for (int m = 0; m < R; ++m)
#pragma unroll
        for (int j = 0; j < TN; ++j) acc[m][j] = 0.f;

    auto K0of = [&](int t) { return ((t + phase) & (NT - 1)) * KT; };

    auto loadA = [&](int K0) {
#pragma unroll
        for (int r = 0; r < R; ++r)
#pragma unroll
            for (int d = 0; d < 2; ++d)
                a[r][d] = *reinterpret_cast<const float4*>(Abase + (size_t)r * N + K0 + d * 256);
    };
    auto writeA = [&]() {
#pragma unroll
        for (int r = 0; r < R; ++r)
#pragma unroll
            for (int d = 0; d < 2; ++d)
                *reinterpret_cast<float4*>(&wl[r * KT + d * 256 + lane * 4]) = a[r][d];
    };
    auto loadP = [&](int K0) {
#pragma unroll
        for (int ks = 0; ks < 8; ++ks)
#pragma unroll
            for (int t = 0; t < 4; ++t)
#pragma unroll
                for (int j = 0; j < PJ; ++j)
                    p[ks][t][j] = *reinterpret_cast<const float4*>(
                        Pm + (size_t)(K0 + ks * 64 + kg * 4 + t) * F + c0 + j * 4);
    };
    auto comp = [&]() {
#pragma unroll
        for (int ks = 0; ks < 8; ++ks) {
#pragma unroll
            for (int m = 0; m < R; ++m) {
                const float4 av = *reinterpret_cast<const float4*>(&wl[m * KT + ks * 64 + kg * 4]);
#pragma unroll
                for (int t = 0; t < 4; ++t) {
                    const float s = (t == 0) ? av.x : (t == 1) ? av.y : (t == 2) ? av.z : av.w;
#pragma unroll
                    for (int j = 0; j < PJ; ++j) {
                        acc[m][j * 4 + 0] += s * p[ks][t][j].x;
                        acc[m][j * 4 + 1] += s * p[ks][t][j].y;
                        acc[m][j * 4 + 2] += s * p[ks][t][j].z;
                        acc[m][j * 4 + 3] += s * p[ks][t][j].w;
                    }
                }
            }
        }
    };
    auto waitA = [&]() {  // wait until only the A-prefetch (2R loads) remains
        if constexpr (R == 8) asm volatile("s_waitcnt vmcnt(16)" ::: "memory");
        else                  asm volatile("s_waitcnt vmcnt(8)" ::: "memory");
    };

    // prologue: LDS<-A(0); P(0) landed; A(1) in flight
    loadA(K0of(0));
    writeA();  // compiler inserts the vmcnt wait for a[] here
    loadP(K0of(0));
    loadA(K0of(1));
    __builtin_amdgcn_sched_barrier(0);
    waitA();
    __builtin_amdgcn_sched_barrier(0);

    for (int t = 0; t < NT; ++t) {
        comp();
        if (t + 1 < NT) {
            __builtin_amdgcn_sched_barrier(0);
            asm volatile("s_waitcnt vmcnt(0)" ::: "memory");  // A(t+1) regs landed
            __builtin_amdgcn_sched_barrier(0);
            writeA();
            loadP(K0of(t + 1));  // issued BEFORE next A: counted wait lands it
            if (t + 2 < NT) {
                loadA(K0of(t + 2));
                __builtin_amdgcn_sched_barrier(0);
                waitA();
            } else {
                __builtin_amdgcn_sched_barrier(0);
                asm volatile("s_waitcnt vmcnt(0)" ::: "memory");
            }
            __builtin_amdgcn_sched_barrier(0);
        }
    }

    // reduce across the 16 k-groups
#pragma unroll
    for (int m = 0; m < R; ++m)
#pragma unroll
        for (int j = 0; j < TN; ++j) {
            float v = acc[m][j];
            v += __shfl_xor(v, 1);
            v += __shfl_xor(v, 2);
            v += __shfl_xor(v, 4);
            v += __shfl_xor(v, 8);
            acc[m][j] = v;
        }
    if (kg == 0) {
#pragma unroll
        for (int m = 0; m < R; ++m)
#pragma unroll
            for (int j = 0; j < PJ; ++j) {
                float4 r;
                r.x = fmaxf(acc[m][j * 4 + 0] + bias[c0 + j * 4 + 0], 0.f);
                r.y = fmaxf(acc[m][j * 4 + 1] + bias[c0 + j * 4 + 1], 0.f);
                r.z = fmaxf(acc[m][j * 4 + 2] + bias[c0 + j * 4 + 2], 0.f);
                r.w = fmaxf(acc[m][j * 4 + 3] + bias[c0 + j * 4 + 3], 0.f);
                *reinterpret_cast<float4*>(
                    &o[(size_t)(rowW + m) * ostride + c0 + j * 4]) = r;
            }
    }
}

// ------- kernel 5: per-block partials of Z_h = sum e^{s}, U_h = sum e^{s}(h.Wd_h)
// tanh in [-1,1] -> softmax without max-subtraction is safe.
__global__ void k_att_pool(const float* __restrict__ h, const float* __restrict__ Watt,
                           const float* __restrict__ Wd, float* __restrict__ partials) {
    __shared__ float sWa[64 * 3];
    __shared__ float sWd[192];
    for (int i = threadIdx.x; i < 192; i += blockDim.x) {
        sWa[i] = Watt[i];
        sWd[i] = Wd[i];
    }
    __syncthreads();
    const int n = blockIdx.x * blockDim.x + threadIdx.x;  // 32*256 == N exactly
    float hv[64];
#pragma unroll
    for (int q = 0; q < 16; ++q)
        *reinterpret_cast<float4*>(&hv[q * 4]) =
            *reinterpret_cast<const float4*>(&h[(size_t)n * 64 + q * 4]);
    float s0 = 0.f, s1 = 0.f, s2 = 0.f;
#pragma unroll
    for (int d = 0; d < 64; ++d) {
        s0 += hv[d] * sWa[d * 3 + 0];
        s1 += hv[d] * sWa[d * 3 + 1];
        s2 += hv[d] * sWa[d * 3 + 2];
    }
    float dot0 = 0.f, dot1 = 0.f, dot2 = 0.f;
#pragma unroll
    for (int d = 0; d < 64; ++d) {
        dot0 += hv[d] * sWd[0 * 64 + d];
        dot1 += hv[d] * sWd[1 * 64 + d];
        dot2 += hv[d] * sWd[2 * 64 + d];
    }
    const float e0 = expf(tanhf(s0));
    const float e1 = expf(tanhf(s1));
    const float e2 = expf(tanhf(s2));
    float vals[6] = {e0, e1, e2, e0 * dot0, e1 * dot1, e2 * dot2};
#pragma unroll
    for (int i = 0; i < 6; ++i) {
        float v = vals[i];
#pragma unroll
        for (int off = 1; off < 64; off <<= 1) v += __shfl_xor(v, off);
        vals[i] = v;
    }
    __shared__ float sred[4][6];
    const int wave = threadIdx.x >> 6, lane = threadIdx.x & 63;
    if (lane == 0) {
#pragma unroll
        for (int i = 0; i < 6; ++i) sred[wave][i] = vals[i];
    }
    __syncthreads();
    if (threadIdx.x == 0) {
#pragma unroll
        for (int i = 0; i < 6; ++i)
            partials[blockIdx.x * 6 + i] = sred[0][i] + sred[1][i] + sred[2][i] + sred[3][i];
    }
}

// ------------- kernel 6: out = sum_h U_h/Z_h + b_dense -------------
__global__ void k_att_final(const float* __restrict__ partials, const float* __restrict__ bd,
                            float* __restrict__ out) {
    if (threadIdx.x == 0) {
        float Z0 = 0.f, Z1 = 0.f, Z2 = 0.f, U0 = 0.f, U1 = 0.f, U2 = 0.f;
        for (int b = 0; b < 32; ++b) {
            Z0 += partials[b * 6 + 0];
            Z1 += partials[b * 6 + 1];
            Z2 += partials[b * 6 + 2];
            U0 += partials[b * 6 + 3];
            U1 += partials[b * 6 + 4];
            U2 += partials[b * 6 + 5];
        }
        out[0] = U0 / Z0 + U1 / Z1 + U2 / Z2 + bd[0];
    }
}

extern "C" void kernel_launch(void* const* d_in, const int* in_sizes, int n_in,
                              void* d_out, int out_size, void* d_ws, size_t ws_size,
                              hipStream_t stream) {
    const float* x_int   = (const float*)d_in[0];
    const float* x_nh    = (const float*)d_in[1];
    const float* adj_int = (const float*)d_in[2];
    const float* adj_nh  = (const float*)d_in[3];
    const float* W1_int  = (const float*)d_in[4];
    const float* b1_int  = (const float*)d_in[5];
    const float* W1_nh   = (const float*)d_in[6];
    const float* b1_nh   = (const float*)d_in[7];
    const float* W2_int  = (const float*)d_in[8];
    const float* b2_int  = (const float*)d_in[9];
    const float* W2_nh   = (const float*)d_in[10];
    const float* b2_nh   = (const float*)d_in[11];
    const float* W_att   = (const float*)d_in[12];
    const float* W_dense = (const float*)d_in[13];
    const float* b_dense = (const float*)d_in[14];

    float* ws = (float*)d_ws;
    float* P1_0 = ws;                        // [8192,16]
    float* P1_1 = ws + 131072;
    float* H1_0 = ws + 262144;               // [8192,16]
    float* H1_1 = ws + 393216;
    float* P2_0 = ws + 524288;               // [8192,32]
    float* P2_1 = ws + 786432;
    float* hcat = ws + 1048576;              // [8192,64] = [H2_int | H2_nh]
    float* partials = ws + 1572864;          // [32,6]
    float* out = (float*)d_out;

    k_dense_in<<<dim3(32, 2), 256, 0, stream>>>(x_int, x_nh, W1_int, W1_nh, P1_0, P1_1);
    k_spmm<16, 8><<<dim3(256, 2), 256, 0, stream>>>(adj_int, adj_nh, P1_0, P1_1,
                                                    b1_int, b1_nh, H1_0, H1_1, 16);
    k_dense_mid<<<dim3(32, 2), 256, 0, stream>>>(H1_0, H1_1, W2_int, W2_nh, P2_0, P2_1);
    k_spmm<32, 4><<<dim3(512, 2), 256, 0, stream>>>(adj_int, adj_nh, P2_0, P2_1,
                                                    b2_int, b2_nh, hcat, hcat + 32, 64);
    k_att_pool<<<32, 256, 0, stream>>>(hcat, W_att, W_dense, partials);
    k_att_final<<<1, 64, 0, stream>>>(partials, b_dense, out);
}

// Round 6
// 626.485 us; speedup vs baseline: 4.7044x; 4.7044x over previous
//
#include <hip/hip_runtime.h>

// GNN27: two-branch diffusion GCN (N=8192, F_IN=11, F1=16, F2=32) + multi-head
// tanh-attention pooling. All fp32. Memory-bound on the two 268MB adjacencies,
// each streamed twice -> 1.07GB unique traffic.
//
// History: R1 direct loads w/ 4x addr duplication -> 680 GB/s. R2-R4
// global_load_lds staging -> ~1 TB/s (DMA path serializes). R5 reg-streamed +
// big P arrays -> 256-reg spill, 3.8GB scratch traffic... at 2.9 TB/s, proving
// plain VMEM streams fast. R6: flat-TLP design. Waves split F (wave owns F/4
// cols), share the block's 8 A-rows via L1 (raw s_barrier keeps them in step,
// no vmcnt drain). Every A and P load is one contiguous 1KB wave burst, no
// duplication. P read from a transposed PT[F][N] copy (L2-resident rereads).
// 2-deep A prefetch in regs; loadP before loadA(next) so counted waits land P
// without retiring the A prefetch. No LDS in the hot kernel at all.

constexpr int N = 8192;

// ---------------- kernel 1: P1T = (x @ W1)^T   ([16][N]) ----------------
__global__ void k_dense_in(const float* __restrict__ x0, const float* __restrict__ x1,
                           const float* __restrict__ W0, const float* __restrict__ W1,
                           float* __restrict__ o0, float* __restrict__ o1) {
    const int branch = blockIdx.y;
    const float* __restrict__ x = branch ? x1 : x0;
    const float* __restrict__ W = branch ? W1 : W0;
    float* __restrict__ o = branch ? o1 : o0;
    __shared__ float sW[11 * 16];
    if (threadIdx.x < 176) sW[threadIdx.x] = W[threadIdx.x];
    __syncthreads();
    const int n = blockIdx.x * blockDim.x + threadIdx.x;  // grid.x*256 == N exactly
    float xr[11];
#pragma unroll
    for (int j = 0; j < 11; ++j) xr[j] = x[n * 11 + j];
    float acc[16];
#pragma unroll
    for (int f = 0; f < 16; ++f) acc[f] = 0.f;
#pragma unroll
    for (int j = 0; j < 11; ++j)
#pragma unroll
        for (int f = 0; f < 16; ++f) acc[f] += xr[j] * sW[j * 16 + f];
#pragma unroll
    for (int f = 0; f < 16; ++f) o[f * N + n] = acc[f];  // transposed, coalesced
}

// ---------------- kernel 3: P2T = (H1 @ W2)^T   ([32][N]) ----------------
__global__ void k_dense_mid(const float* __restrict__ h0, const float* __restrict__ h1,
                            const float* __restrict__ W0, const float* __restrict__ W1,
                            float* __restrict__ o0, float* __restrict__ o1) {
    const int branch = blockIdx.y;
    const float* __restrict__ h = branch ? h1 : h0;
    const float* __restrict__ W = branch ? W1 : W0;
    float* __restrict__ o = branch ? o1 : o0;
    __shared__ float sW[16 * 32];
    for (int i = threadIdx.x; i < 512; i += blockDim.x) sW[i] = W[i];
    __syncthreads();
    const int n = blockIdx.x * blockDim.x + threadIdx.x;
    float hr[16];
#pragma unroll
    for (int q = 0; q < 4; ++q)
        *reinterpret_cast<float4*>(&hr[q * 4]) =
            *reinterpret_cast<const float4*>(&h[n * 16 + q * 4]);
    float acc[32];
#pragma unroll
    for (int f = 0; f < 32; ++f) acc[f] = 0.f;
#pragma unroll
    for (int j = 0; j < 16; ++j)
#pragma unroll
        for (int f = 0; f < 32; ++f) acc[f] += hr[j] * sW[j * 32 + f];
#pragma unroll
    for (int f = 0; f < 32; ++f) o[f * N + n] = acc[f];  // transposed, coalesced
}

// -------- kernels 2 & 4: H = relu(A @ P + b), flat-TLP reg streaming -------
// Block = 8 rows, 4 waves. Wave w owns f-slice [w*F/4, (w+1)*F/4). All 4
// waves read the SAME A rows (L1 broadcast; raw s_barrier per half-tile keeps
// them aligned). Lane l covers k-offsets 4l..4l+3 of each 256-float K-tile:
// A load = A[row][K0+4l..] (1KB contiguous burst), P load = PT[f][K0+4l..]
// (1KB contiguous, L2-resident). 2-deep A prefetch in registers. Epilogue:
// log-compaction shfl reduce (no runtime register indexing).
template <int F>
__global__ __launch_bounds__(256, F == 16 ? 3 : 2) void k_spmm(
    const float* __restrict__ A0, const float* __restrict__ A1,
    const float* __restrict__ PT0, const float* __restrict__ PT1,
    const float* __restrict__ b0, const float* __restrict__ b1,
    float* __restrict__ o0, float* __restrict__ o1, int ostride) {
    constexpr int Fw = F / 4;   // f-cols per wave: 4 or 8
    constexpr int M = 8;        // rows per block (shared by all 4 waves)
    constexpr int KT = 256;     // K-tile (floats)
    constexpr int NT = N / KT;  // 32
    constexpr int NV = M * Fw;  // partials per lane: 32 or 64
    const int branch = blockIdx.y;
    const float* __restrict__ A = branch ? A1 : A0;
    const float* __restrict__ PT = branch ? PT1 : PT0;
    const float* __restrict__ bias = branch ? b1 : b0;
    float* __restrict__ o = branch ? o1 : o0;

    const int lane = threadIdx.x & 63;
    const int wave = threadIdx.x >> 6;
    const int f0 = wave * Fw;
    const int r0 = blockIdx.x * M;
    const int phase = blockIdx.x & (NT - 1);  // K-rotation (per block)

    const float* __restrict__ Abase = A + (size_t)r0 * N + 4 * lane;
    const float* __restrict__ Pbase = PT + (size_t)f0 * N + 4 * lane;

    float4 a[M], an[M], pt[Fw];
    float acc[M][Fw];
#pragma unroll
    for (int m = 0; m < M; ++m)
#pragma unroll
        for (int j = 0; j < Fw; ++j) acc[m][j] = 0.f;

    auto K0of = [&](int t) { return ((t + phase) & (NT - 1)) * KT; };
    auto loadA = [&](float4(&buf)[M], int K0) {
#pragma unroll
        for (int m = 0; m < M; ++m)
            buf[m] = *reinterpret_cast<const float4*>(Abase + (size_t)m * N + K0);
    };
    auto loadP = [&](int K0) {
#pragma unroll
        for (int j = 0; j < Fw; ++j)
            pt[j] = *reinterpret_cast<const float4*>(Pbase + (size_t)j * N + K0);
    };
    auto fmas = [&](float4(&buf)[M]) {
#pragma unroll
        for (int m = 0; m < M; ++m)
#pragma unroll
            for (int j = 0; j < Fw; ++j) {
                acc[m][j] += buf[m].x * pt[j].x;
                acc[m][j] += buf[m].y * pt[j].y;
                acc[m][j] += buf[m].z * pt[j].z;
                acc[m][j] += buf[m].w * pt[j].w;
            }
    };

    loadA(a, K0of(0));
    for (int t = 0; t < NT; t += 2) {
        loadP(K0of(t));                           // issued before next-A
        loadA(an, K0of(t + 1));                   // 2-deep A prefetch
        __builtin_amdgcn_s_barrier();             // align waves (no vmcnt drain)
        fmas(a);                                  // waits pt, leaves `an` flying
        loadP(K0of(t + 1));
        if (t + 2 < NT) loadA(a, K0of(t + 2));
        __builtin_amdgcn_s_barrier();
        fmas(an);
    }

    // log-compaction reduce over the 64 k-lanes; lane l ends with partial
    // index i == l (mod NV), fully summed. No runtime register indexing.
    float v[NV];
#pragma unroll
    for (int i = 0; i < NV; ++i) v[i] = acc[i / Fw][i % Fw];
#pragma unroll
    for (int s = 0; (NV >> s) > 1; ++s) {
        const int bit = (lane >> s) & 1;
#pragma unroll
        for (int i = 0; i < (NV >> s); i += 2) {
            const float t0 = __shfl_xor(v[i], 1 << s);
            const float t1 = __shfl_xor(v[i + 1], 1 << s);
            v[i >> 1] = bit ? (v[i + 1] + t1) : (v[i] + t0);
        }
    }
    float r = v[0];
    if constexpr (NV == 32) r += __shfl_xor(r, 32);  // merge lane halves

    const int m = lane / Fw;  // row within block (address only)
    const int j = lane % Fw;  // col within wave's f-slice
    if (F == 32 || lane < 32) {
        const float val = fmaxf(r + bias[f0 + j], 0.f);
        o[(size_t)(r0 + m) * ostride + f0 + j] = val;
    }
}

// ------- kernel 5: per-block partials of Z_h = sum e^{s}, U_h = sum e^{s}(h.Wd_h)
// tanh in [-1,1] -> softmax without max-subtraction is safe.
__global__ void k_att_pool(const float* __restrict__ h, const float* __restrict__ Watt,
                           const float* __restrict__ Wd, float* __restrict__ partials) {
    __shared__ float sWa[64 * 3];
    __shared__ float sWd[192];
    for (int i = threadIdx.x; i < 192; i += blockDim.x) {
        sWa[i] = Watt[i];
        sWd[i] = Wd[i];
    }
    __syncthreads();
    const int n = blockIdx.x * blockDim.x + threadIdx.x;  // 32*256 == N exactly
    float hv[64];
#pragma unroll
    for (int q = 0; q < 16; ++q)
        *reinterpret_cast<float4*>(&hv[q * 4]) =
            *reinterpret_cast<const float4*>(&h[(size_t)n * 64 + q * 4]);
    float s0 = 0.f, s1 = 0.f, s2 = 0.f;
#pragma unroll
    for (int d = 0; d < 64; ++d) {
        s0 += hv[d] * sWa[d * 3 + 0];
        s1 += hv[d] * sWa[d * 3 + 1];
        s2 += hv[d] * sWa[d * 3 + 2];
    }
    float dot0 = 0.f, dot1 = 0.f, dot2 = 0.f;
#pragma unroll
    for (int d = 0; d < 64; ++d) {
        dot0 += hv[d] * sWd[0 * 64 + d];
        dot1 += hv[d] * sWd[1 * 64 + d];
        dot2 += hv[d] * sWd[2 * 64 + d];
    }
    const float e0 = expf(tanhf(s0));
    const float e1 = expf(tanhf(s1));
    const float e2 = expf(tanhf(s2));
    float vals[6] = {e0, e1, e2, e0 * dot0, e1 * dot1, e2 * dot2};
#pragma unroll
    for (int i = 0; i < 6; ++i) {
        float v = vals[i];
#pragma unroll
        for (int off = 1; off < 64; off <<= 1) v += __shfl_xor(v, off);
        vals[i] = v;
    }
    __shared__ float sred[4][6];
    const int wave = threadIdx.x >> 6, lane = threadIdx.x & 63;
    if (lane == 0) {
#pragma unroll
        for (int i = 0; i < 6; ++i) sred[wave][i] = vals[i];
    }
    __syncthreads();
    if (threadIdx.x == 0) {
#pragma unroll
        for (int i = 0; i < 6; ++i)
            partials[blockIdx.x * 6 + i] = sred[0][i] + sred[1][i] + sred[2][i] + sred[3][i];
    }
}

// ------------- kernel 6: out = sum_h U_h/Z_h + b_dense -------------
__global__ void k_att_final(const float* __restrict__ partials, const float* __restrict__ bd,
                            float* __restrict__ out) {
    if (threadIdx.x == 0) {
        float Z0 = 0.f, Z1 = 0.f, Z2 = 0.f, U0 = 0.f, U1 = 0.f, U2 = 0.f;
        for (int b = 0; b < 32; ++b) {
            Z0 += partials[b * 6 + 0];
            Z1 += partials[b * 6 + 1];
            Z2 += partials[b * 6 + 2];
            U0 += partials[b * 6 + 3];
            U1 += partials[b * 6 + 4];
            U2 += partials[b * 6 + 5];
        }
        out[0] = U0 / Z0 + U1 / Z1 + U2 / Z2 + bd[0];
    }
}

extern "C" void kernel_launch(void* const* d_in, const int* in_sizes, int n_in,
                              void* d_out, int out_size, void* d_ws, size_t ws_size,
                              hipStream_t stream) {
    const float* x_int   = (const float*)d_in[0];
    const float* x_nh    = (const float*)d_in[1];
    const float* adj_int = (const float*)d_in[2];
    const float* adj_nh  = (const float*)d_in[3];
    const float* W1_int  = (const float*)d_in[4];
    const float* b1_int  = (const float*)d_in[5];
    const float* W1_nh   = (const float*)d_in[6];
    const float* b1_nh   = (const float*)d_in[7];
    const float* W2_int  = (const float*)d_in[8];
    const float* b2_int  = (const float*)d_in[9];
    const float* W2_nh   = (const float*)d_in[10];
    const float* b2_nh   = (const float*)d_in[11];
    const float* W_att   = (const float*)d_in[12];
    const float* W_dense = (const float*)d_in[13];
    const float* b_dense = (const float*)d_in[14];

    float* ws = (float*)d_ws;
    float* P1T_0 = ws;                       // [16][8192]
    float* P1T_1 = ws + 131072;
    float* H1_0  = ws + 262144;              // [8192][16] row-major
    float* H1_1  = ws + 393216;
    float* P2T_0 = ws + 524288;              // [32][8192]
    float* P2T_1 = ws + 786432;
    float* hcat  = ws + 1048576;             // [8192][64] = [H2_int | H2_nh]
    float* partials = ws + 1572864;          // [32,6]
    float* out = (float*)d_out;

    k_dense_in<<<dim3(32, 2), 256, 0, stream>>>(x_int, x_nh, W1_int, W1_nh, P1T_0, P1T_1);
    k_spmm<16><<<dim3(1024, 2), 256, 0, stream>>>(adj_int, adj_nh, P1T_0, P1T_1,
                                                  b1_int, b1_nh, H1_0, H1_1, 16);
    k_dense_mid<<<dim3(32, 2), 256, 0, stream>>>(H1_0, H1_1, W2_int, W2_nh, P2T_0, P2T_1);
    k_spmm<32><<<dim3(1024, 2), 256, 0, stream>>>(adj_int, adj_nh, P2T_0, P2T_1,
                                                  b2_int, b2_nh, hcat, hcat + 32, 64);
    k_att_pool<<<32, 256, 0, stream>>>(hcat, W_att, W_dense, partials);
    k_att_final<<<1, 64, 0, stream>>>(partials, b_dense, out);
}